// Round 14
// baseline (612.002 us; speedup 1.0000x reference)
//
#include <hip/hip_runtime.h>
#include <hip/hip_fp16.h>

constexpr int K_DIM = 128;

typedef _Float16 f16x8 __attribute__((ext_vector_type(8)));
typedef float f32x4 __attribute__((ext_vector_type(4)));

#define GLOAD16(g, l) __builtin_amdgcn_global_load_lds( \
    (const __attribute__((address_space(1))) void*)(g), \
    (__attribute__((address_space(3))) void*)(l), 16, 0, 0)

// ================= Bucketed CSR build =================
__global__ __launch_bounds__(256) void bcount_k(const int* __restrict__ dst, int E,
    int* __restrict__ bcount, int NBr) {
  __shared__ int h[256];
  const int tid = threadIdx.x;
  h[tid] = 0;
  __syncthreads();
  for (int t = blockIdx.x * 256 + tid; t < E; t += gridDim.x * 256)
    atomicAdd(&h[dst[t] >> 8], 1);
  __syncthreads();
  if (tid < NBr && h[tid]) atomicAdd(&bcount[tid], h[tid]);
}

__global__ __launch_bounds__(256) void bscan_k(const int* __restrict__ bcount,
    int* __restrict__ bstart, int* __restrict__ bcursor, int NBr) {
  __shared__ int sh[256];
  const int t = threadIdx.x;
  sh[t] = (t < NBr) ? bcount[t] : 0;
  __syncthreads();
  for (int off = 1; off < 256; off <<= 1) {
    int w = (t >= off) ? sh[t - off] : 0;
    __syncthreads();
    sh[t] += w;
    __syncthreads();
  }
  if (t < NBr) {
    int ex = t ? sh[t - 1] : 0;
    bstart[t] = ex;
    bcursor[t] = ex;
  }
  if (t == NBr - 1) bstart[NBr] = sh[t];
}

__global__ __launch_bounds__(256) void bscatter_k(const int* __restrict__ ei, int E,
    int* __restrict__ bcursor, unsigned* __restrict__ brec, int NBr) {
  __shared__ int h[256];
  __shared__ int base[256];
  const int tid = threadIdx.x;
  h[tid] = 0;
  __syncthreads();
  const int chunk = (E + gridDim.x - 1) / gridDim.x;
  const int s = blockIdx.x * chunk;
  const int e = min(E, s + chunk);
  for (int t = s + tid; t < e; t += 256) atomicAdd(&h[ei[E + t] >> 8], 1);
  __syncthreads();
  if (tid < NBr && h[tid]) base[tid] = atomicAdd(&bcursor[tid], h[tid]);
  __syncthreads();
  for (int t = s + tid; t < e; t += 256) {
    int src = ei[t];
    int d = ei[E + t];
    int bk = d >> 8;
    int p = atomicAdd(&base[bk], 1);
    brec[p] = ((unsigned)src << 8) | (unsigned)(d & 255);
  }
}

// Pass C: per-node CSR split into 4 src-tiles (tile = src / tdiv, tdiv = ceil(n/4)).
// colidx ushort. tptr[node*4+t] = segment start; contiguity (within and across
// nodes) gives end = tptr[idx+1]; tptr[4n] = E+n.
__global__ __launch_bounds__(256) void bcsr_k(const unsigned* __restrict__ brec,
    const int* __restrict__ bstart, int n, int E, int tdiv,
    unsigned short* __restrict__ colidx, float* __restrict__ dinv,
    int* __restrict__ tptr) {
  __shared__ int s_cnt[256 * 4];
  __shared__ int s_cur[256 * 4];
  __shared__ int s_scan[256];
  __shared__ int s_lrp[257];
  const int b = blockIdx.x, tid = threadIdx.x;
  const int node0 = b << 8;
  const int LC = min(256, n - node0);
  const int rs = bstart[b], cnt = bstart[b + 1] - rs;

  #pragma unroll
  for (int t = 0; t < 4; ++t) s_cnt[tid * 4 + t] = 0;
  __syncthreads();
  for (int i = tid; i < cnt; i += 256) {
    unsigned r = brec[rs + i];
    int src = (int)(r >> 8);
    atomicAdd(&s_cnt[(r & 255) * 4 + src / tdiv], 1);
  }
  if (tid < LC) atomicAdd(&s_cnt[tid * 4 + (node0 + tid) / tdiv], 1);
  __syncthreads();

  int deg = 0;
  #pragma unroll
  for (int t = 0; t < 4; ++t) deg += s_cnt[tid * 4 + t];
  s_scan[tid] = deg;
  __syncthreads();
  for (int off = 1; off < 256; off <<= 1) {
    int w = (tid >= off) ? s_scan[tid - off] : 0;
    __syncthreads();
    s_scan[tid] += w;
    __syncthreads();
  }
  s_lrp[tid + 1] = s_scan[tid];
  if (tid == 0) s_lrp[0] = 0;
  __syncthreads();

  const int gbase = rs + node0;
  if (tid < LC) {
    int node = node0 + tid;
    int off = gbase + s_lrp[tid];
    dinv[node] = rsqrtf((float)(s_lrp[tid + 1] - s_lrp[tid]));
    #pragma unroll
    for (int t = 0; t < 4; ++t) {
      tptr[(size_t)node * 4 + t] = off;
      s_cur[tid * 4 + t] = off;
      off += s_cnt[tid * 4 + t];
    }
  }
  __syncthreads();
  if (tid < LC) {
    int node = node0 + tid;
    int p = atomicAdd(&s_cur[tid * 4 + node / tdiv], 1);
    colidx[p] = (unsigned short)node;
  }
  for (int i = tid; i < cnt; i += 256) {
    unsigned r = brec[rs + i];
    int d = r & 255;
    int src = (int)(r >> 8);
    int p = atomicAdd(&s_cur[d * 4 + src / tdiv], 1);
    colidx[p] = (unsigned short)src;
  }
  if (b == (int)gridDim.x - 1 && tid == 0) tptr[(size_t)n * 4] = E + n;
}

// ====== fused prep: x fp32 -> fp16 Z ; W fp32 -> fp16 hi/lo transposed ======
__global__ __launch_bounds__(256) void prep_k(const float* __restrict__ x,
    __half* __restrict__ z, long total4,
    const float* __restrict__ W1, const float* __restrict__ W2,
    const float* __restrict__ W3, const float* __restrict__ W4,
    __half* __restrict__ wth, __half* __restrict__ wtl) {
  long t = (long)blockIdx.x * 256 + threadIdx.x;
  if (t < total4) {
    float4 v = reinterpret_cast<const float4*>(x)[t];
    union { __half2 h[2]; uint2 u; } uu;
    uu.h[0] = __floats2half2_rn(v.x, v.y);
    uu.h[1] = __floats2half2_rn(v.z, v.w);
    reinterpret_cast<uint2*>(z)[t] = uu.u;
  }
  if (t < 57344) {
    int id = (int)t;
    const float* W;
    int nout, base, rem;
    if (id < 49152) {
      int l = id / 16384;
      W = (l == 0) ? W1 : (l == 1) ? W2 : W3;
      nout = 128;
      base = l * 16384;
      rem = id - base;
    } else {
      W = W4;
      nout = 64;
      base = 49152;
      rem = id - base;
    }
    int k = rem / nout, c = rem % nout;
    float w = W[k * nout + c];
    __half hi = __float2half_rn(w);
    __half lo = __float2half_rn(w - __half2float(hi));
    wth[base + c * 128 + k] = hi;
    wtl[base + c * 128 + k] = lo;
  }
}

// ======= MFMA GEMM: H[r] = dinv[r] * (Z @ W)[r]  (fp16 Z, 2-term fp16 W) =======
template<int NOUT>
__global__ __launch_bounds__(256) void gemm_mfma_k(
    const __half* __restrict__ Z,
    const __half* __restrict__ Wh, const __half* __restrict__ Wl,
    const float* __restrict__ dinv, __half* __restrict__ H, int n) {
  constexpr int NT = NOUT / 32;
  __shared__ __half Az[32][32];
  __shared__ __half Bh[NOUT][32];
  __shared__ __half Bl[NOUT][32];
  const int tid = threadIdx.x;
  const int lane = tid & 63;
  const int w = tid >> 6;
  const int r16 = lane & 15;
  const int kb = lane >> 4;
  const int row0 = blockIdx.x * 32;
  const int rh = w & 1;
  const int ch = w >> 1;
  const int sw = (r16 + (r16 >> 2)) & 3;

  f32x4 acc[NT];
  #pragma unroll
  for (int t = 0; t < NT; ++t)
    #pragma unroll
    for (int q = 0; q < 4; ++q) acc[t][q] = 0.f;

  char* AzB = (char*)&Az[0][0];
  char* BhB = (char*)&Bh[0][0];
  char* BlB = (char*)&Bl[0][0];

  for (int kc = 0; kc < 128; kc += 32) {
    __syncthreads();
    if (w < 2) {
      int r = tid >> 2;
      int q = (tid & 3) ^ ((r + (r >> 2)) & 3);
      int rc = row0 + r; rc = (rc < n) ? rc : (n - 1);
      GLOAD16(Z + (size_t)rc * 128 + kc + q * 8, AzB + w * 1024);
    }
    {
      int c = tid >> 2;
      int q = (tid & 3) ^ ((c + (c >> 2)) & 3);
      GLOAD16(Wh + (size_t)c * 128 + kc + q * 8, BhB + w * 1024);
      GLOAD16(Wl + (size_t)c * 128 + kc + q * 8, BlB + w * 1024);
      if constexpr (NOUT == 128) {
        int i1 = tid + 256;
        int c1 = i1 >> 2;
        int q1 = (i1 & 3) ^ ((c1 + (c1 >> 2)) & 3);
        GLOAD16(Wh + (size_t)c1 * 128 + kc + q1 * 8, BhB + 4096 + w * 1024);
        GLOAD16(Wl + (size_t)c1 * 128 + kc + q1 * 8, BlB + 4096 + w * 1024);
      }
    }
    __syncthreads();

    const int ao = (kb ^ sw) * 8;
    f16x8 az = *(const f16x8*)&Az[rh * 16 + r16][ao];
    #pragma unroll
    for (int t = 0; t < NT; ++t) {
      int c = ch * (NOUT / 2) + t * 16 + r16;
      f16x8 bh = *(const f16x8*)&Bh[c][ao];
      f16x8 bl = *(const f16x8*)&Bl[c][ao];
      acc[t] = __builtin_amdgcn_mfma_f32_16x16x32_f16(az, bh, acc[t], 0, 0, 0);
      acc[t] = __builtin_amdgcn_mfma_f32_16x16x32_f16(az, bl, acc[t], 0, 0, 0);
    }
  }

  #pragma unroll
  for (int q = 0; q < 4; ++q) {
    int grow = row0 + rh * 16 + kb * 4 + q;
    if (grow < n) {
      float dsc = dinv[grow];
      #pragma unroll
      for (int t = 0; t < NT; ++t) {
        int col = ch * (NOUT / 2) + t * 16 + r16;
        H[(size_t)grow * NOUT + col] = __float2half(dsc * acc[t][q]);
      }
    }
  }
}

// ===== src-tiled CSR aggregation: 4 phases, persistent co-resident grid =====
// 2048 blocks x 4 waves = 8192 waves (8 blocks/CU, all co-resident).
// Wave owns nodes W, W+8192, ... (NPW=7). Phase t gathers only sources in
// tile t (3.2 MB H-window, L2-resident per XCD; all resident waves sweep the
// same window -> cross-XCD L3 sharing). Accumulators persist across phases.
__global__ __launch_bounds__(256) void agg128_k(const __half* __restrict__ H,
    const unsigned short* __restrict__ colidx, const int* __restrict__ tptr,
    const float* __restrict__ dinv, const float* __restrict__ bias,
    __half* __restrict__ Z, int n) {
  const int wave = threadIdx.x >> 6;
  const int lane = threadIdx.x & 63;
  const int W = blockIdx.x * 4 + wave;   // 0..8191
  const __half2* H2 = reinterpret_cast<const __half2*>(H);
  constexpr int NPW = 7;

  float ax[NPW], ay[NPW];
  #pragma unroll
  for (int i = 0; i < NPW; ++i) { ax[i] = 0.f; ay[i] = 0.f; }

  for (int t = 0; t < 4; ++t) {
    #pragma unroll
    for (int i = 0; i < NPW; ++i) {
      int nd = W + i * 8192;
      if (nd < n) {
        const int s = tptr[(size_t)nd * 4 + t];
        const int e = tptr[(size_t)nd * 4 + t + 1];
        for (int base = s; base < e; base += 64) {
          int m = e - base;
          int c = (int)__builtin_nontemporal_load(&colidx[base + ((lane < m) ? lane : 0)]);
          int kmax = (m < 64) ? m : 64;
          int k = 0;
          for (; k + 7 < kmax; k += 8) {
            int cc[8];
            float2 hh[8];
            #pragma unroll
            for (int u = 0; u < 8; ++u) cc[u] = __shfl(c, k + u);
            #pragma unroll
            for (int u = 0; u < 8; ++u) hh[u] = __half22float2(H2[(size_t)cc[u] * 64 + lane]);
            #pragma unroll
            for (int u = 0; u < 8; ++u) { ax[i] += hh[u].x; ay[i] += hh[u].y; }
          }
          for (; k < kmax; ++k) {
            int ck = __shfl(c, k);
            float2 h = __half22float2(H2[(size_t)ck * 64 + lane]);
            ax[i] += h.x;
            ay[i] += h.y;
          }
        }
      }
    }
  }

  float2 b2 = reinterpret_cast<const float2*>(bias)[lane];
  #pragma unroll
  for (int i = 0; i < NPW; ++i) {
    int nd = W + i * 8192;
    if (nd < n) {
      float d = dinv[nd];
      float ox = fmaxf(fmaf(d, ax[i], b2.x), 0.f);
      float oy = fmaxf(fmaf(d, ay[i], b2.y), 0.f);
      __half2 hv = __floats2half2_rn(ox, oy);
      unsigned vv = *reinterpret_cast<unsigned*>(&hv);
      __builtin_nontemporal_store(vv, reinterpret_cast<unsigned*>(Z) + (size_t)nd * 64 + lane);
    }
  }
}

// final layer: 64-wide H, fp32 out, no relu — same tiled persistent structure
__global__ __launch_bounds__(256) void agg64_k(const __half* __restrict__ H,
    const unsigned short* __restrict__ colidx, const int* __restrict__ tptr,
    const float* __restrict__ dinv, const float* __restrict__ bias,
    float* __restrict__ out, int n) {
  const int wave = threadIdx.x >> 6;
  const int lane = threadIdx.x & 63;
  const int W = blockIdx.x * 4 + wave;
  constexpr int NPW = 7;

  float a0[NPW];
  #pragma unroll
  for (int i = 0; i < NPW; ++i) a0[i] = 0.f;

  for (int t = 0; t < 4; ++t) {
    #pragma unroll
    for (int i = 0; i < NPW; ++i) {
      int nd = W + i * 8192;
      if (nd < n) {
        const int s = tptr[(size_t)nd * 4 + t];
        const int e = tptr[(size_t)nd * 4 + t + 1];
        for (int base = s; base < e; base += 64) {
          int m = e - base;
          int c = (int)__builtin_nontemporal_load(&colidx[base + ((lane < m) ? lane : 0)]);
          int kmax = (m < 64) ? m : 64;
          int k = 0;
          for (; k + 7 < kmax; k += 8) {
            int cc[8];
            float hh[8];
            #pragma unroll
            for (int u = 0; u < 8; ++u) cc[u] = __shfl(c, k + u);
            #pragma unroll
            for (int u = 0; u < 8; ++u) hh[u] = __half2float(H[(size_t)cc[u] * 64 + lane]);
            #pragma unroll
            for (int u = 0; u < 8; ++u) a0[i] += hh[u];
          }
          for (; k < kmax; ++k) {
            int ck = __shfl(c, k);
            a0[i] += __half2float(H[(size_t)ck * 64 + lane]);
          }
        }
      }
    }
  }

  float bv = bias[lane];
  #pragma unroll
  for (int i = 0; i < NPW; ++i) {
    int nd = W + i * 8192;
    if (nd < n) {
      float o = fmaf(dinv[nd], a0[i], bv);
      __builtin_nontemporal_store(o, &out[(size_t)nd * 64 + lane]);
    }
  }
}

extern "C" void kernel_launch(void* const* d_in, const int* in_sizes, int n_in,
                              void* d_out, int out_size, void* d_ws, size_t ws_size,
                              hipStream_t stream) {
  const int n = in_sizes[0] / K_DIM;   // 50000
  const int E = in_sizes[1] / 2;       // 1600000
  const int NBr = (n + 255) >> 8;
  const int tdiv = (n + 3) >> 2;       // 12500

  const float* x  = (const float*)d_in[0];
  const int*   ei = (const int*)d_in[1];
  const float* W1 = (const float*)d_in[2];
  const float* b1 = (const float*)d_in[3];
  const float* W2 = (const float*)d_in[4];
  const float* b2 = (const float*)d_in[5];
  const float* W3 = (const float*)d_in[6];
  const float* b3 = (const float*)d_in[7];
  const float* W4 = (const float*)d_in[8];
  const float* b4 = (const float*)d_in[9];
  float* out = (float*)d_out;

  char* ws = (char*)d_ws;
  size_t off = 0;
  auto alloc = [&](size_t bytes) -> void* {
    void* p = ws + off;
    off += (bytes + 255) & ~(size_t)255;
    return p;
  };
  int*      bcount  = (int*)     alloc(256 * 4);
  int*      bstart  = (int*)     alloc(257 * 4);
  int*      bcursor = (int*)     alloc(256 * 4);
  unsigned* brec    = (unsigned*)alloc((size_t)E * 4);
  unsigned short* colidx = (unsigned short*)alloc((size_t)(E + n) * 2);
  int*      tptr    = (int*)     alloc(((size_t)n * 4 + 1) * 4);
  float*    dinv    = (float*)   alloc((size_t)n * 4);
  __half*   Z       = (__half*)  alloc((size_t)n * 128 * 2);
  __half*   hH      = (__half*)  alloc((size_t)n * 128 * 2);
  __half*   wth     = (__half*)  alloc((size_t)57344 * 2);
  __half*   wtl     = (__half*)  alloc((size_t)57344 * 2);

  // CSR build
  hipMemsetAsync(bcount, 0, 256 * 4, stream);
  bcount_k<<<512, 256, 0, stream>>>(ei + E, E, bcount, NBr);
  bscan_k<<<1, 256, 0, stream>>>(bcount, bstart, bcursor, NBr);
  bscatter_k<<<256, 256, 0, stream>>>(ei, E, bcursor, brec, NBr);
  bcsr_k<<<NBr, 256, 0, stream>>>(brec, bstart, n, E, tdiv, colidx, dinv, tptr);

  // fused input convert + weight prep
  const long total4 = (long)n * 32;
  prep_k<<<(int)((total4 + 255) / 256), 256, 0, stream>>>(x, Z, total4,
                                                          W1, W2, W3, W4, wth, wtl);

  const int gb = (n + 31) / 32;
  const int agb = 2048;   // 8 blocks/CU, all co-resident

  // layer 1
  gemm_mfma_k<128><<<gb, 256, 0, stream>>>(Z, wth, wtl, dinv, hH, n);
  agg128_k<<<agb, 256, 0, stream>>>(hH, colidx, tptr, dinv, b1, Z, n);
  // layer 2
  gemm_mfma_k<128><<<gb, 256, 0, stream>>>(Z, wth + 16384, wtl + 16384, dinv, hH, n);
  agg128_k<<<agb, 256, 0, stream>>>(hH, colidx, tptr, dinv, b2, Z, n);
  // layer 3
  gemm_mfma_k<128><<<gb, 256, 0, stream>>>(Z, wth + 32768, wtl + 32768, dinv, hH, n);
  agg128_k<<<agb, 256, 0, stream>>>(hH, colidx, tptr, dinv, b3, Z, n);
  // layer 4 (128 -> 64)
  gemm_mfma_k<64><<<gb, 256, 0, stream>>>(Z, wth + 49152, wtl + 49152, dinv, hH, n);
  agg64_k<<<agb, 256, 0, stream>>>(hH, colidx, tptr, dinv, b4, out, n);
}

// Round 15
// 316.615 us; speedup vs baseline: 1.9330x; 1.9330x over previous
//
#include <hip/hip_runtime.h>
#include <hip/hip_fp16.h>

constexpr int K_DIM = 128;

typedef _Float16 f16x8 __attribute__((ext_vector_type(8)));
typedef float f32x4 __attribute__((ext_vector_type(4)));

#define GLOAD16(g, l) __builtin_amdgcn_global_load_lds( \
    (const __attribute__((address_space(1))) void*)(g), \
    (__attribute__((address_space(3))) void*)(l), 16, 0, 0)

// ================= Bucketed CSR build =================
__global__ void zerob_k(int* __restrict__ bcount, int NBr) {
  int t = threadIdx.x;
  if (t < NBr) bcount[t] = 0;
}

__global__ __launch_bounds__(256) void bcount_k(const int* __restrict__ dst, int E,
    int* __restrict__ bcount, int NBr) {
  __shared__ int h[256];
  const int tid = threadIdx.x;
  h[tid] = 0;
  __syncthreads();
  for (int t = blockIdx.x * 256 + tid; t < E; t += gridDim.x * 256)
    atomicAdd(&h[dst[t] >> 8], 1);
  __syncthreads();
  if (tid < NBr && h[tid]) atomicAdd(&bcount[tid], h[tid]);
}

__global__ __launch_bounds__(256) void bscan_k(const int* __restrict__ bcount,
    int* __restrict__ bstart, int* __restrict__ bcursor, int NBr) {
  __shared__ int sh[256];
  const int t = threadIdx.x;
  sh[t] = (t < NBr) ? bcount[t] : 0;
  __syncthreads();
  for (int off = 1; off < 256; off <<= 1) {
    int w = (t >= off) ? sh[t - off] : 0;
    __syncthreads();
    sh[t] += w;
    __syncthreads();
  }
  if (t < NBr) {
    int ex = t ? sh[t - 1] : 0;
    bstart[t] = ex;
    bcursor[t] = ex;
  }
  if (t == NBr - 1) bstart[NBr] = sh[t];
}

__global__ __launch_bounds__(256) void bscatter_k(const int* __restrict__ ei, int E,
    int* __restrict__ bcursor, unsigned* __restrict__ brec, int NBr) {
  __shared__ int h[256];
  __shared__ int base[256];
  const int tid = threadIdx.x;
  h[tid] = 0;
  __syncthreads();
  const int chunk = (E + gridDim.x - 1) / gridDim.x;
  const int s = blockIdx.x * chunk;
  const int e = min(E, s + chunk);
  for (int t = s + tid; t < e; t += 256) atomicAdd(&h[ei[E + t] >> 8], 1);
  __syncthreads();
  if (tid < NBr && h[tid]) base[tid] = atomicAdd(&bcursor[tid], h[tid]);
  __syncthreads();
  for (int t = s + tid; t < e; t += 256) {
    int src = ei[t];
    int d = ei[E + t];
    int bk = d >> 8;
    int p = atomicAdd(&base[bk], 1);
    brec[p] = ((unsigned)src << 8) | (unsigned)(d & 255);
  }
}

__global__ __launch_bounds__(256) void bcsr_k(const unsigned* __restrict__ brec,
    const int* __restrict__ bstart, int n, int E,
    int* __restrict__ rowptr, int* __restrict__ colidx, float* __restrict__ dinv) {
  __shared__ int s_deg[256];
  __shared__ int s_cur[256];
  __shared__ int s_lrp[257];
  const int b = blockIdx.x, tid = threadIdx.x;
  const int node0 = b << 8;
  const int LC = min(256, n - node0);
  const int rs = bstart[b], cnt = bstart[b + 1] - rs;

  s_deg[tid] = (tid < LC) ? 1 : 0;
  __syncthreads();
  for (int i = tid; i < cnt; i += 256) atomicAdd(&s_deg[brec[rs + i] & 255], 1);
  __syncthreads();
  s_cur[tid] = s_deg[tid];
  __syncthreads();
  for (int off = 1; off < 256; off <<= 1) {
    int w = (tid >= off) ? s_cur[tid - off] : 0;
    __syncthreads();
    s_cur[tid] += w;
    __syncthreads();
  }
  s_lrp[tid + 1] = s_cur[tid];
  if (tid == 0) s_lrp[0] = 0;
  __syncthreads();

  const int gbase = rs + node0;
  if (tid < LC) {
    int p = s_lrp[tid];
    colidx[gbase + p] = node0 + tid;
    s_cur[tid] = p + 1;
    rowptr[node0 + tid] = gbase + p;
    dinv[node0 + tid] = rsqrtf((float)(s_lrp[tid + 1] - p));
  }
  __syncthreads();
  for (int i = tid; i < cnt; i += 256) {
    unsigned r = brec[rs + i];
    int p = atomicAdd(&s_cur[r & 255], 1);
    colidx[gbase + p] = (int)(r >> 8);
  }
  if (b == (int)gridDim.x - 1 && tid == 0) rowptr[n] = E + n;
}

// ================= input convert: fp32 -> fp16 Z =================
__global__ __launch_bounds__(256) void split_k(const float* __restrict__ x,
    __half* __restrict__ z, long total4) {
  long t = (long)blockIdx.x * 256 + threadIdx.x;
  if (t >= total4) return;
  float4 v = reinterpret_cast<const float4*>(x)[t];
  union { __half2 h[2]; uint2 u; } uu;
  uu.h[0] = __floats2half2_rn(v.x, v.y);
  uu.h[1] = __floats2half2_rn(v.z, v.w);
  reinterpret_cast<uint2*>(z)[t] = uu.u;
}

// ====== W prep: fp32 W[k][c] -> fp16 hi/lo, transposed Wt[c][k] ======
__global__ __launch_bounds__(256) void wprep_k(
    const float* __restrict__ W1, const float* __restrict__ W2,
    const float* __restrict__ W3, const float* __restrict__ W4,
    __half* __restrict__ wth, __half* __restrict__ wtl) {
  int id = blockIdx.x * 256 + threadIdx.x;
  if (id >= 57344) return;
  const float* W;
  int nout, base, rem;
  if (id < 49152) {
    int l = id / 16384;
    W = (l == 0) ? W1 : (l == 1) ? W2 : W3;
    nout = 128;
    base = l * 16384;
    rem = id - base;
  } else {
    W = W4;
    nout = 64;
    base = 49152;
    rem = id - base;
  }
  int k = rem / nout, c = rem % nout;
  float w = W[k * nout + c];
  __half hi = __float2half_rn(w);
  __half lo = __float2half_rn(w - __half2float(hi));
  wth[base + c * 128 + k] = hi;
  wtl[base + c * 128 + k] = lo;
}

// ======= MFMA GEMM: H[r] = dinv[r] * (Z @ W)[r]  (fp16 Z, 2-term fp16 W) =======
// 64-row tiles, 4 waves, wave = 16 rows x NOUT cols. LDS XOR-oct-swizzled:
// source k-oct q of row r stored at dest oct q ^ g(r), g(r) = (r + (r>>2)) & 3.
template<int NOUT>
__global__ __launch_bounds__(256) void gemm_mfma_k(
    const __half* __restrict__ Z,
    const __half* __restrict__ Wh, const __half* __restrict__ Wl,
    const float* __restrict__ dinv, __half* __restrict__ H, int n) {
  constexpr int NT = NOUT / 16;
  __shared__ __half Az[64][32];
  __shared__ __half Bh[NOUT][32];
  __shared__ __half Bl[NOUT][32];
  const int tid = threadIdx.x;
  const int lane = tid & 63;
  const int w = tid >> 6;
  const int r16 = lane & 15;
  const int kb = lane >> 4;
  const int row0 = blockIdx.x * 64;
  const int sw = (r16 + (r16 >> 2)) & 3;   // g(row) for all rows this lane reads

  f32x4 acc[NT];
  #pragma unroll
  for (int t = 0; t < NT; ++t)
    #pragma unroll
    for (int q = 0; q < 4; ++q) acc[t][q] = 0.f;

  char* AzB = (char*)&Az[0][0];
  char* BhB = (char*)&Bh[0][0];
  char* BlB = (char*)&Bl[0][0];

  for (int kc = 0; kc < 128; kc += 32) {
    __syncthreads();
    {
      // A: slot=tid -> row r=tid>>2, dest oct j=tid&3, src oct q=j^g(r)
      int r = tid >> 2;
      int q = (tid & 3) ^ ((r + (r >> 2)) & 3);
      int rc = row0 + r; rc = (rc < n) ? rc : (n - 1);
      GLOAD16(Z + (size_t)rc * 128 + kc + q * 8, AzB + w * 1024);
    }
    {
      // B: slot=tid (+256 for NOUT=128) -> col c=slot>>2, same swizzle
      int c = tid >> 2;
      int q = (tid & 3) ^ ((c + (c >> 2)) & 3);
      GLOAD16(Wh + (size_t)c * 128 + kc + q * 8, BhB + w * 1024);
      GLOAD16(Wl + (size_t)c * 128 + kc + q * 8, BlB + w * 1024);
      if constexpr (NOUT == 128) {
        int i1 = tid + 256;
        int c1 = i1 >> 2;
        int q1 = (i1 & 3) ^ ((c1 + (c1 >> 2)) & 3);
        GLOAD16(Wh + (size_t)c1 * 128 + kc + q1 * 8, BhB + 4096 + w * 1024);
        GLOAD16(Wl + (size_t)c1 * 128 + kc + q1 * 8, BlB + 4096 + w * 1024);
      }
    }
    __syncthreads();

    const int ao = (kb ^ sw) * 8;
    f16x8 az = *(const f16x8*)&Az[w * 16 + r16][ao];
    #pragma unroll
    for (int t = 0; t < NT; ++t) {
      f16x8 bh = *(const f16x8*)&Bh[t * 16 + r16][ao];
      f16x8 bl = *(const f16x8*)&Bl[t * 16 + r16][ao];
      acc[t] = __builtin_amdgcn_mfma_f32_16x16x32_f16(az, bh, acc[t], 0, 0, 0);
      acc[t] = __builtin_amdgcn_mfma_f32_16x16x32_f16(az, bl, acc[t], 0, 0, 0);
    }
  }

  // epilogue: H[row] = dinv[row] * acc (fp16); C/D: col=r16, row=kb*4+q
  #pragma unroll
  for (int q = 0; q < 4; ++q) {
    int grow = row0 + w * 16 + kb * 4 + q;
    if (grow < n) {
      float dsc = dinv[grow];
      #pragma unroll
      for (int t = 0; t < NT; ++t)
        H[(size_t)grow * NOUT + t * 16 + r16] = __float2half(dsc * acc[t][q]);
    }
  }
}

// ================= CSR aggregation (prescaled H, shfl-broadcast) =============
// Wave = 1 node, lane = feature pair. H prescaled by dinv[src]:
// out_i = dinv[i] * sum_c H'[c] + b ; relu, fp16 Z store.
__global__ __launch_bounds__(256) void agg128_k(const __half* __restrict__ H,
    const int* __restrict__ rowptr, const int* __restrict__ colidx,
    const float* __restrict__ dinv, const float* __restrict__ bias,
    __half* __restrict__ Z, int n) {
  const int wave = threadIdx.x >> 6;
  const int lane = threadIdx.x & 63;
  const int node = blockIdx.x * 4 + wave;
  if (node >= n) return;
  const int s = rowptr[node], e = rowptr[node + 1];
  const __half2* H2 = reinterpret_cast<const __half2*>(H);

  float ax = 0.f, ay = 0.f;
  for (int base = s; base < e; base += 64) {
    int m = e - base;
    int c = __builtin_nontemporal_load(&colidx[base + ((lane < m) ? lane : 0)]);
    int kmax = (m < 64) ? m : 64;
    int k = 0;
    for (; k + 7 < kmax; k += 8) {
      int cc[8];
      float2 hh[8];
      #pragma unroll
      for (int u = 0; u < 8; ++u) cc[u] = __shfl(c, k + u);
      #pragma unroll
      for (int u = 0; u < 8; ++u) hh[u] = __half22float2(H2[(size_t)cc[u] * 64 + lane]);
      #pragma unroll
      for (int u = 0; u < 8; ++u) { ax += hh[u].x; ay += hh[u].y; }
    }
    for (; k < kmax; ++k) {
      int ck = __shfl(c, k);
      float2 h = __half22float2(H2[(size_t)ck * 64 + lane]);
      ax += h.x;
      ay += h.y;
    }
  }
  float d = dinv[node];
  float2 b2 = reinterpret_cast<const float2*>(bias)[lane];
  float ox = fmaxf(fmaf(d, ax, b2.x), 0.f);
  float oy = fmaxf(fmaf(d, ay, b2.y), 0.f);
  __half2 hv = __floats2half2_rn(ox, oy);
  unsigned vv = *reinterpret_cast<unsigned*>(&hv);
  __builtin_nontemporal_store(vv, reinterpret_cast<unsigned*>(Z) + (size_t)node * 64 + lane);
}

// final layer: 64-wide, fp32 out, no relu
__global__ __launch_bounds__(256) void agg64_k(const __half* __restrict__ H,
    const int* __restrict__ rowptr, const int* __restrict__ colidx,
    const float* __restrict__ dinv, const float* __restrict__ bias,
    float* __restrict__ out, int n) {
  const int wave = threadIdx.x >> 6;
  const int lane = threadIdx.x & 63;
  const int node = blockIdx.x * 4 + wave;
  if (node >= n) return;
  const int s = rowptr[node], e = rowptr[node + 1];

  float a0 = 0.f;
  for (int base = s; base < e; base += 64) {
    int m = e - base;
    int c = __builtin_nontemporal_load(&colidx[base + ((lane < m) ? lane : 0)]);
    int kmax = (m < 64) ? m : 64;
    int k = 0;
    for (; k + 7 < kmax; k += 8) {
      int cc[8];
      float hh[8];
      #pragma unroll
      for (int u = 0; u < 8; ++u) cc[u] = __shfl(c, k + u);
      #pragma unroll
      for (int u = 0; u < 8; ++u) hh[u] = __half2float(H[(size_t)cc[u] * 64 + lane]);
      #pragma unroll
      for (int u = 0; u < 8; ++u) a0 += hh[u];
    }
    for (; k < kmax; ++k) {
      int ck = __shfl(c, k);
      a0 += __half2float(H[(size_t)ck * 64 + lane]);
    }
  }
  float o = fmaf(dinv[node], a0, bias[lane]);
  __builtin_nontemporal_store(o, &out[(size_t)node * 64 + lane]);
}

extern "C" void kernel_launch(void* const* d_in, const int* in_sizes, int n_in,
                              void* d_out, int out_size, void* d_ws, size_t ws_size,
                              hipStream_t stream) {
  const int n = in_sizes[0] / K_DIM;   // 50000
  const int E = in_sizes[1] / 2;       // 1600000
  const int NBr = (n + 255) >> 8;

  const float* x  = (const float*)d_in[0];
  const int*   ei = (const int*)d_in[1];
  const float* W1 = (const float*)d_in[2];
  const float* b1 = (const float*)d_in[3];
  const float* W2 = (const float*)d_in[4];
  const float* b2 = (const float*)d_in[5];
  const float* W3 = (const float*)d_in[6];
  const float* b3 = (const float*)d_in[7];
  const float* W4 = (const float*)d_in[8];
  const float* b4 = (const float*)d_in[9];
  float* out = (float*)d_out;

  char* ws = (char*)d_ws;
  size_t off = 0;
  auto alloc = [&](size_t bytes) -> void* {
    void* p = ws + off;
    off += (bytes + 255) & ~(size_t)255;
    return p;
  };
  int*      bcount  = (int*)     alloc(256 * 4);
  int*      bstart  = (int*)     alloc(257 * 4);
  int*      bcursor = (int*)     alloc(256 * 4);
  unsigned* brec    = (unsigned*)alloc((size_t)E * 4);
  int*      rowptr  = (int*)     alloc((size_t)(n + 1) * 4);
  int*      colidx  = (int*)     alloc((size_t)(E + n) * 4);
  float*    dinv    = (float*)   alloc((size_t)n * 4);
  __half*   Z       = (__half*)  alloc((size_t)n * 128 * 2);   // fp16 gemm input
  __half*   hH      = (__half*)  alloc((size_t)n * 128 * 2);   // fp16 pre-agg (prescaled)
  __half*   wth     = (__half*)  alloc((size_t)57344 * 2);
  __half*   wtl     = (__half*)  alloc((size_t)57344 * 2);

  // CSR build
  zerob_k<<<1, 256, 0, stream>>>(bcount, NBr);
  bcount_k<<<512, 256, 0, stream>>>(ei + E, E, bcount, NBr);
  bscan_k<<<1, 256, 0, stream>>>(bcount, bstart, bcursor, NBr);
  bscatter_k<<<256, 256, 0, stream>>>(ei, E, bcursor, brec, NBr);
  bcsr_k<<<NBr, 256, 0, stream>>>(brec, bstart, n, E, rowptr, colidx, dinv);

  // input convert + weight prep
  const long total4 = (long)n * 32;
  split_k<<<(int)((total4 + 255) / 256), 256, 0, stream>>>(x, Z, total4);
  wprep_k<<<224, 256, 0, stream>>>(W1, W2, W3, W4, wth, wtl);

  const int gb = (n + 63) / 64;   // 782 blocks
  const int ab = (n + 3) / 4;

  // layer 1
  gemm_mfma_k<128><<<gb, 256, 0, stream>>>(Z, wth, wtl, dinv, hH, n);
  agg128_k<<<ab, 256, 0, stream>>>(hH, rowptr, colidx, dinv, b1, Z, n);
  // layer 2
  gemm_mfma_k<128><<<gb, 256, 0, stream>>>(Z, wth + 16384, wtl + 16384, dinv, hH, n);
  agg128_k<<<ab, 256, 0, stream>>>(hH, rowptr, colidx, dinv, b2, Z, n);
  // layer 3
  gemm_mfma_k<128><<<gb, 256, 0, stream>>>(Z, wth + 32768, wtl + 32768, dinv, hH, n);
  agg128_k<<<ab, 256, 0, stream>>>(hH, rowptr, colidx, dinv, b3, Z, n);
  // layer 4 (128 -> 64)
  gemm_mfma_k<64><<<gb, 256, 0, stream>>>(Z, wth + 49152, wtl + 49152, dinv, hH, n);
  agg64_k<<<ab, 256, 0, stream>>>(hH, rowptr, colidx, dinv, b4, out, n);
}